// Round 5
// baseline (1150.440 us; speedup 1.0000x reference)
//
#include <hip/hip_runtime.h>
#include <hip/hip_bf16.h>
#include <hip/hip_fp16.h>

#define T_ 2048
#define B_ 64
#define NIN_ 128
#define H_ 256
#define NOUT_ 128
#define TB_ (T_*B_)
#define BH_ (B_*H_)

typedef _Float16 h8 __attribute__((ext_vector_type(8)));
typedef _Float16 h4 __attribute__((ext_vector_type(4)));
typedef _Float16 half2_t __attribute__((ext_vector_type(2)));
typedef float f32x4 __attribute__((ext_vector_type(4)));

// LDS-only barrier: do NOT drain vmcnt (global loads/stores stay in flight).
#define BAR_LGKM() asm volatile("s_waitcnt lgkmcnt(0)\n\ts_barrier" ::: "memory")

__device__ __forceinline__ half2_t mk2(_Float16 a, _Float16 b) { half2_t r; r.x = a; r.y = b; return r; }
__device__ __forceinline__ half2_t f2h2(float a, float b) { return mk2((_Float16)a, (_Float16)b); }
__device__ __forceinline__ float fdot2(half2_t a, half2_t b, float c) {
    return __builtin_amdgcn_fdot2(a, b, c, false);
}
__device__ __forceinline__ h8 cvt8(float4 a, float4 b) {
    h8 r;
    r[0] = (_Float16)a.x; r[1] = (_Float16)a.y; r[2] = (_Float16)a.z; r[3] = (_Float16)a.w;
    r[4] = (_Float16)b.x; r[5] = (_Float16)b.y; r[6] = (_Float16)b.z; r[7] = (_Float16)b.w;
    return r;
}
__device__ __forceinline__ h8 ld_cvt8(const float* __restrict__ p) {
    const float4* q = (const float4*)p;
    return cvt8(q[0], q[1]);
}
// cross-lane helpers (VALU DPP quad-perm + one LDS swizzle for xor-4)
__device__ __forceinline__ float dpp1(float x) {   // lane ^ 1
    return __builtin_bit_cast(float, __builtin_amdgcn_mov_dpp(__builtin_bit_cast(int, x), 0xB1, 0xF, 0xF, true));
}
__device__ __forceinline__ float dpp2(float x) {   // lane ^ 2
    return __builtin_bit_cast(float, __builtin_amdgcn_mov_dpp(__builtin_bit_cast(int, x), 0x4E, 0xF, 0xF, true));
}
__device__ __forceinline__ float swz4(float x) {   // lane ^ 4
    return __builtin_bit_cast(float, __builtin_amdgcn_ds_swizzle(__builtin_bit_cast(int, x), 0x101F));
}

// ---------------------------------------------------------------------------
// K1: xp[TB][256](f16) = x[TB][128](f32) @ W_ih^T + (b_ih+b_hh)   (MFMA C^T)
// next-tile x loads issued before epilogue; double-buffered st; 1 lgkm barrier/iter
// ---------------------------------------------------------------------------
__global__ __launch_bounds__(256, 2) void k1_xproj(
    const float* __restrict__ x,
    const float* __restrict__ w_ih,
    const float* __restrict__ b_ih,
    const float* __restrict__ b_hh,
    _Float16* __restrict__ xp)
{
    const int tid = threadIdx.x;
    const int lane = tid & 63, wave = tid >> 6;
    const int m = lane & 15, quad = lane >> 4;

    h8 af[4][4];
    #pragma unroll
    for (int i = 0; i < 4; ++i)
        #pragma unroll
        for (int kt = 0; kt < 4; ++kt)
            af[i][kt] = ld_cvt8(w_ih + (size_t)(wave*64 + i*16 + m) * NIN_ + kt*32 + quad*8);

    float bias[4][4];
    #pragma unroll
    for (int i = 0; i < 4; ++i)
        #pragma unroll
        for (int r = 0; r < 4; ++r) {
            int c = wave*64 + i*16 + quad*4 + r;
            bias[i][r] = b_ih[c] + b_hh[c];
        }

    __shared__ __align__(16) _Float16 st[2][16][264];

    // preload tile 0
    float4 xr[4][2];
    {
        const size_t n0 = (size_t)blockIdx.x * 256;
        #pragma unroll
        for (int kt = 0; kt < 4; ++kt) {
            const float4* q = (const float4*)(x + (n0 + m) * NIN_ + kt*32 + quad*8);
            xr[kt][0] = q[0]; xr[kt][1] = q[1];
        }
    }

    for (int rt = 0; rt < 16; ++rt) {
        const size_t n0 = (size_t)blockIdx.x * 256 + rt * 16;

        h8 bf[4];
        #pragma unroll
        for (int kt = 0; kt < 4; ++kt) bf[kt] = cvt8(xr[kt][0], xr[kt][1]);

        // issue next tile's loads now; they stay in flight across the epilogue
        if (rt < 15) {
            #pragma unroll
            for (int kt = 0; kt < 4; ++kt) {
                const float4* q = (const float4*)(x + (n0 + 16 + m) * NIN_ + kt*32 + quad*8);
                xr[kt][0] = q[0]; xr[kt][1] = q[1];
            }
        }

        f32x4 acc[4];
        #pragma unroll
        for (int i = 0; i < 4; ++i) acc[i] = (f32x4){0,0,0,0};
        #pragma unroll
        for (int i = 0; i < 4; ++i)
            #pragma unroll
            for (int kt = 0; kt < 4; ++kt)
                acc[i] = __builtin_amdgcn_mfma_f32_16x16x32_f16(af[i][kt], bf[kt], acc[i], 0, 0, 0);

        const int p = rt & 1;
        #pragma unroll
        for (int i = 0; i < 4; ++i) {
            h4 hv;
            #pragma unroll
            for (int r = 0; r < 4; ++r) hv[r] = (_Float16)(acc[i][r] + bias[i][r]);
            *(uint2*)&st[p][m][wave*64 + i*16 + quad*4] = __builtin_bit_cast(uint2, hv);
        }
        BAR_LGKM();
        #pragma unroll
        for (int it = 0; it < 2; ++it) {
            int idx = tid + it*256;
            int r = idx >> 5, c8 = (idx & 31) * 8;
            uint4 v = *(const uint4*)&st[p][r][c8];
            *(uint4*)(xp + (n0 + r) * H_ + c8) = v;
        }
    }
}

// ---------------------------------------------------------------------------
// K2: sequential scan. 64 WGs (one batch each), 512 threads (8 waves).
// lane split: ks = tid&7 (8-way k-split, 32-wide slice), jg = tid>>3 (0..63),
// thread computes 4 partial outputs j = jg*4+r over k in [ks*32, ks*32+32).
// h in LDS as 8 chunks of 32 f16 padded to 40 (bank-disjoint 8-way broadcast).
// Reduce across 8 ks-lanes: DPP xor1, xor2 + ds_swizzle xor4; lanes ks and
// ks+4 both end owning j = jg*4 + (ks&3); the ks<4 lane writes.
// LDS-only barrier per step; xp prefetched 4 deep stays in flight.
// ---------------------------------------------------------------------------
__global__ __launch_bounds__(512, 1) void k2_scan(
    const _Float16* __restrict__ xp,       // [T][B][H] f16
    const float* __restrict__ w_hh,        // [H][H] f32
    _Float16* __restrict__ hs)             // [T][B][H] f16
{
    const int tid = threadIdx.x;
    const int ks = tid & 7;
    const int jg = tid >> 3;
    const int b = blockIdx.x;
    const int j0 = jg * 4;
    const int jown = j0 + (ks & 3);
    const bool wr_own = (ks < 4);

    // w2[r][p] = W_hh[j0+r][ks*32 + 2p .. +1]   (64 half2 VGPRs)
    half2_t w2[4][16];
    #pragma unroll
    for (int r = 0; r < 4; ++r) {
        const float4* wr = (const float4*)(w_hh + (size_t)(j0 + r) * H_ + ks*32);
        #pragma unroll
        for (int q = 0; q < 8; ++q) {
            float4 d = wr[q];
            w2[r][2*q]   = f2h2(d.x, d.y);
            w2[r][2*q+1] = f2h2(d.z, d.w);
        }
    }

    // h buffers: 8 chunks x (32 data + 8 pad) f16
    __shared__ __align__(16) _Float16 hb[2][320];
    {
        unsigned int* z = (unsigned int*)&hb[0][0];
        if (tid < 320) z[tid] = 0u;
    }
    __syncthreads();

    const _Float16* xpl = xp + (size_t)b * H_ + jown;
    _Float16*       hsl = hs + (size_t)b * H_ + jown;
    const int lown = ((jown >> 5) * 40) + (jown & 31);

    _Float16 pf[4];
    #pragma unroll
    for (int i = 0; i < 4; ++i) pf[i] = xpl[(size_t)i * BH_];

#define K2_STEP(T, RB, WB, PI)                                                 \
    {                                                                          \
        const h8* hp = (const h8*)(&RB[ks*40]);                                \
        h8 bv[4];                                                              \
        _Pragma("unroll")                                                      \
        for (int i = 0; i < 4; ++i) bv[i] = hp[i];                             \
        const int tn = ((T) + 4 < T_) ? (T) + 4 : T_ - 1;                      \
        _Float16 nf = xpl[(size_t)tn * BH_];                                   \
        float acc[4][2] = {{0,0},{0,0},{0,0},{0,0}};                           \
        const half2_t* hh = (const half2_t*)&bv[0];                            \
        _Pragma("unroll")                                                      \
        for (int p = 0; p < 16; ++p) {                                         \
            _Pragma("unroll")                                                  \
            for (int r = 0; r < 4; ++r)                                        \
                acc[r][p&1] = fdot2(hh[p], w2[r][p], acc[r][p&1]);             \
        }                                                                      \
        float a0 = acc[0][0] + acc[0][1];                                      \
        float a1 = acc[1][0] + acc[1][1];                                      \
        float a2 = acc[2][0] + acc[2][1];                                      \
        float a3 = acc[3][0] + acc[3][1];                                      \
        const bool kb1 = (ks & 1), kb2 = (ks & 2);                             \
        float keep01 = kb1 ? a1 : a0, send01 = kb1 ? a0 : a1;                  \
        float v01 = keep01 + dpp1(send01);                                     \
        float keep23 = kb1 ? a3 : a2, send23 = kb1 ? a2 : a3;                  \
        float v23 = keep23 + dpp1(send23);                                     \
        float keepA = kb2 ? v23 : v01, sendA = kb2 ? v01 : v23;                \
        float v = keepA + dpp2(sendA);                                         \
        v += swz4(v);                                                          \
        float sv = v + (float)pf[PI];                                          \
        pf[PI] = nf;                                                           \
        float e  = __expf(2.0f * sv);                                          \
        float hn = fmaf(-2.0f, __builtin_amdgcn_rcpf(e + 1.0f), 1.0f);         \
        _Float16 hh16 = (_Float16)hn;                                          \
        if (wr_own) {                                                          \
            WB[lown] = hh16;                                                   \
            hsl[(size_t)(T) * BH_] = hh16;                                     \
        }                                                                      \
        BAR_LGKM();                                                            \
    }

    for (int t = 0; t < T_; t += 4) {
        K2_STEP(t + 0, hb[0], hb[1], 0)
        K2_STEP(t + 1, hb[1], hb[0], 1)
        K2_STEP(t + 2, hb[0], hb[1], 2)
        K2_STEP(t + 3, hb[1], hb[0], 3)
    }
#undef K2_STEP
}

// ---------------------------------------------------------------------------
// K3: out[TB][128](f32) = hs[TB][256](f16) @ W_out^T + b_out   (MFMA C^T)
// next-tile hs loads issued before epilogue; double-buffered st; 1 barrier/iter
// ---------------------------------------------------------------------------
__global__ __launch_bounds__(256, 2) void k3_out(
    const _Float16* __restrict__ hs,
    const float* __restrict__ w_out,
    const float* __restrict__ b_out,
    float* __restrict__ out)
{
    const int tid = threadIdx.x;
    const int lane = tid & 63, wave = tid >> 6;
    const int m = lane & 15, quad = lane >> 4;

    h8 af[2][8];
    #pragma unroll
    for (int i = 0; i < 2; ++i)
        #pragma unroll
        for (int kt = 0; kt < 8; ++kt)
            af[i][kt] = ld_cvt8(w_out + (size_t)(wave*32 + i*16 + m) * H_ + kt*32 + quad*8);

    float bias[2][4];
    #pragma unroll
    for (int i = 0; i < 2; ++i)
        #pragma unroll
        for (int r = 0; r < 4; ++r)
            bias[i][r] = b_out[wave*32 + i*16 + quad*4 + r];

    __shared__ __align__(16) float st[2][16][132];

    h8 bf[8];
    {
        const size_t n0 = (size_t)blockIdx.x * 256;
        #pragma unroll
        for (int kt = 0; kt < 8; ++kt)
            bf[kt] = *(const h8*)(hs + (n0 + m) * H_ + kt*32 + quad*8);
    }

    for (int rt = 0; rt < 16; ++rt) {
        const size_t n0 = (size_t)blockIdx.x * 256 + rt * 16;

        h8 cur[8];
        #pragma unroll
        for (int kt = 0; kt < 8; ++kt) cur[kt] = bf[kt];

        if (rt < 15) {
            #pragma unroll
            for (int kt = 0; kt < 8; ++kt)
                bf[kt] = *(const h8*)(hs + (n0 + 16 + m) * H_ + kt*32 + quad*8);
        }

        f32x4 acc[2];
        #pragma unroll
        for (int i = 0; i < 2; ++i) acc[i] = (f32x4){0,0,0,0};
        #pragma unroll
        for (int i = 0; i < 2; ++i)
            #pragma unroll
            for (int kt = 0; kt < 8; ++kt)
                acc[i] = __builtin_amdgcn_mfma_f32_16x16x32_f16(af[i][kt], cur[kt], acc[i], 0, 0, 0);

        const int p = rt & 1;
        #pragma unroll
        for (int i = 0; i < 2; ++i) {
            f32x4 v;
            #pragma unroll
            for (int r = 0; r < 4; ++r) v[r] = acc[i][r] + bias[i][r];
            *(f32x4*)&st[p][m][wave*32 + i*16 + quad*4] = v;
        }
        BAR_LGKM();
        #pragma unroll
        for (int it = 0; it < 2; ++it) {
            int idx = tid + it*256;
            int r = idx >> 5, c4 = (idx & 31) * 4;
            f32x4 v = *(const f32x4*)&st[p][r][c4];
            *(f32x4*)(out + (n0 + r) * NOUT_ + c4) = v;
        }
    }
}

extern "C" void kernel_launch(void* const* d_in, const int* in_sizes, int n_in,
                              void* d_out, int out_size, void* d_ws, size_t ws_size,
                              hipStream_t stream) {
    const float* x     = (const float*)d_in[0];
    const float* w_ih  = (const float*)d_in[1];
    const float* w_hh  = (const float*)d_in[2];
    const float* b_ih  = (const float*)d_in[3];
    const float* b_hh  = (const float*)d_in[4];
    const float* w_out = (const float*)d_in[5];
    const float* b_out = (const float*)d_in[6];

    _Float16* xp    = (_Float16*)d_ws;                 // 67.1 MB
    _Float16* hsbuf = xp + (size_t)TB_ * H_;           // 67.1 MB

    k1_xproj<<<512, 256, 0, stream>>>(x, w_ih, b_ih, b_hh, xp);
    k2_scan <<<B_,  512, 0, stream>>>(xp, w_hh, hsbuf);
    k3_out  <<<512, 256, 0, stream>>>(hsbuf, w_out, b_out, (float*)d_out);
}

// Round 6
// 1118.901 us; speedup vs baseline: 1.0282x; 1.0282x over previous
//
#include <hip/hip_runtime.h>
#include <hip/hip_bf16.h>
#include <hip/hip_fp16.h>

#define T_ 2048
#define B_ 64
#define NIN_ 128
#define H_ 256
#define NOUT_ 128
#define TB_ (T_*B_)
#define BH_ (B_*H_)

typedef _Float16 h8 __attribute__((ext_vector_type(8)));
typedef _Float16 h4 __attribute__((ext_vector_type(4)));
typedef float f32x4 __attribute__((ext_vector_type(4)));

// LDS-only barrier: do NOT drain vmcnt (global loads/stores stay in flight).
#define BAR_LGKM() asm volatile("s_waitcnt lgkmcnt(0)\n\ts_barrier" ::: "memory")

__device__ __forceinline__ h8 cvt8(float4 a, float4 b) {
    h8 r;
    r[0] = (_Float16)a.x; r[1] = (_Float16)a.y; r[2] = (_Float16)a.z; r[3] = (_Float16)a.w;
    r[4] = (_Float16)b.x; r[5] = (_Float16)b.y; r[6] = (_Float16)b.z; r[7] = (_Float16)b.w;
    return r;
}
__device__ __forceinline__ h8 ld_cvt8(const float* __restrict__ p) {
    const float4* q = (const float4*)p;
    return cvt8(q[0], q[1]);
}

// ---------------------------------------------------------------------------
// K1: xp[TB][256](f16) = x[TB][128](f32) @ W_ih^T + (b_ih+b_hh)   (MFMA C^T)
// 1024 WGs x 8 row-tiles; next-tile loads in flight across epilogue.
// ---------------------------------------------------------------------------
__global__ __launch_bounds__(256, 2) void k1_xproj(
    const float* __restrict__ x,
    const float* __restrict__ w_ih,
    const float* __restrict__ b_ih,
    const float* __restrict__ b_hh,
    _Float16* __restrict__ xp)
{
    const int tid = threadIdx.x;
    const int lane = tid & 63, wave = tid >> 6;
    const int m = lane & 15, quad = lane >> 4;

    h8 af[4][4];
    #pragma unroll
    for (int i = 0; i < 4; ++i)
        #pragma unroll
        for (int kt = 0; kt < 4; ++kt)
            af[i][kt] = ld_cvt8(w_ih + (size_t)(wave*64 + i*16 + m) * NIN_ + kt*32 + quad*8);

    float bias[4][4];
    #pragma unroll
    for (int i = 0; i < 4; ++i)
        #pragma unroll
        for (int r = 0; r < 4; ++r) {
            int c = wave*64 + i*16 + quad*4 + r;
            bias[i][r] = b_ih[c] + b_hh[c];
        }

    __shared__ __align__(16) _Float16 st[2][16][264];

    float4 xr[4][2];
    {
        const size_t n0 = (size_t)blockIdx.x * 128;
        #pragma unroll
        for (int kt = 0; kt < 4; ++kt) {
            const float4* q = (const float4*)(x + (n0 + m) * NIN_ + kt*32 + quad*8);
            xr[kt][0] = q[0]; xr[kt][1] = q[1];
        }
    }

    for (int rt = 0; rt < 8; ++rt) {
        const size_t n0 = (size_t)blockIdx.x * 128 + rt * 16;

        h8 bf[4];
        #pragma unroll
        for (int kt = 0; kt < 4; ++kt) bf[kt] = cvt8(xr[kt][0], xr[kt][1]);

        if (rt < 7) {
            #pragma unroll
            for (int kt = 0; kt < 4; ++kt) {
                const float4* q = (const float4*)(x + (n0 + 16 + m) * NIN_ + kt*32 + quad*8);
                xr[kt][0] = q[0]; xr[kt][1] = q[1];
            }
        }

        f32x4 acc[4];
        #pragma unroll
        for (int i = 0; i < 4; ++i) acc[i] = (f32x4){0,0,0,0};
        #pragma unroll
        for (int i = 0; i < 4; ++i)
            #pragma unroll
            for (int kt = 0; kt < 4; ++kt)
                acc[i] = __builtin_amdgcn_mfma_f32_16x16x32_f16(af[i][kt], bf[kt], acc[i], 0, 0, 0);

        const int p = rt & 1;
        #pragma unroll
        for (int i = 0; i < 4; ++i) {
            h4 hv;
            #pragma unroll
            for (int r = 0; r < 4; ++r) hv[r] = (_Float16)(acc[i][r] + bias[i][r]);
            *(uint2*)&st[p][m][wave*64 + i*16 + quad*4] = __builtin_bit_cast(uint2, hv);
        }
        BAR_LGKM();
        #pragma unroll
        for (int it = 0; it < 2; ++it) {
            int idx = tid + it*256;
            int r = idx >> 5, c8 = (idx & 31) * 8;
            uint4 v = *(const uint4*)&st[p][r][c8];
            *(uint4*)(xp + (n0 + r) * H_ + c8) = v;
        }
    }
}

// ---------------------------------------------------------------------------
// K2: sequential scan via MFMA, 64 WGs (one batch each), 256 threads.
// A = h broadcast to all 16 M-rows (quad-uniform b128 LDS reads -> free
// broadcast); every C row equals the true output, so each lane reads its own
// column from acc[quad] (3 cndmask) -- NO cross-lane reduce.
// B = W_hh static B-frags: bf[q][kt] = W_hh[wave*64+q*16+n][kt*32+quad*8..+7]
// (128 VGPRs). 32 MFMA/step/wave, 4 independent 8-deep chains.
// h double-buffered in LDS (256 f16); 1 lgkm-only barrier/step.
// xp prefetched 8 deep in rotating registers.
// ---------------------------------------------------------------------------
__global__ __launch_bounds__(256, 1) void k2_scan(
    const _Float16* __restrict__ xp,       // [T][B][H] f16
    const float* __restrict__ w_hh,        // [H][H] f32
    _Float16* __restrict__ hs)             // [T][B][H] f16
{
    const int tid = threadIdx.x;
    const int lane = tid & 63, wave = tid >> 6;
    const int n = lane & 15, quad = lane >> 4;
    const int b = blockIdx.x;
    const int j = wave*64 + quad*16 + n;    // owned output column

    // B-frags (W_hh), 128 VGPRs
    h8 bf[4][8];
    #pragma unroll
    for (int q = 0; q < 4; ++q)
        #pragma unroll
        for (int kt = 0; kt < 8; ++kt)
            bf[q][kt] = ld_cvt8(w_hh + (size_t)(wave*64 + q*16 + n) * H_ + kt*32 + quad*8);

    __shared__ __align__(16) _Float16 hb[2][256];
    hb[0][tid] = (_Float16)0.0f;
    __syncthreads();

    const _Float16* xpl = xp + (size_t)b * H_ + j;
    _Float16*       hsl = hs + (size_t)b * H_ + j;

    _Float16 pf[8];
    #pragma unroll
    for (int i = 0; i < 8; ++i) pf[i] = xpl[(size_t)i * BH_];

#define K2_STEP(T, RB, WB, S)                                                  \
    {                                                                          \
        const h8* hp = (const h8*)&RB[0];                                      \
        h8 av[8];                                                              \
        _Pragma("unroll")                                                      \
        for (int kt = 0; kt < 8; ++kt) av[kt] = hp[kt*4 + quad];               \
        f32x4 acc[4];                                                          \
        _Pragma("unroll")                                                      \
        for (int q = 0; q < 4; ++q) acc[q] = (f32x4){0,0,0,0};                 \
        _Pragma("unroll")                                                      \
        for (int kt = 0; kt < 8; ++kt)                                         \
            _Pragma("unroll")                                                  \
            for (int q = 0; q < 4; ++q)                                        \
                acc[q] = __builtin_amdgcn_mfma_f32_16x16x32_f16(av[kt], bf[q][kt], acc[q], 0, 0, 0); \
        const int tn = ((T) + 8 < T_) ? (T) + 8 : T_ - 1;                      \
        _Float16 nf = xpl[(size_t)tn * BH_];                                   \
        float v0 = acc[0][0], v1 = acc[1][0], v2 = acc[2][0], v3 = acc[3][0];  \
        float va = (quad & 1) ? v1 : v0;                                       \
        float vb = (quad & 1) ? v3 : v2;                                       \
        float vv = (quad & 2) ? vb : va;                                       \
        float sv = vv + (float)pf[S];                                          \
        pf[S] = nf;                                                            \
        float e  = __expf(2.0f * sv);                                          \
        float hn = fmaf(-2.0f, __builtin_amdgcn_rcpf(e + 1.0f), 1.0f);         \
        _Float16 h16 = (_Float16)hn;                                           \
        WB[j] = h16;                                                           \
        hsl[(size_t)(T) * BH_] = h16;                                          \
        BAR_LGKM();                                                            \
    }

    for (int t = 0; t < T_; t += 8) {
        K2_STEP(t + 0, hb[0], hb[1], 0)
        K2_STEP(t + 1, hb[1], hb[0], 1)
        K2_STEP(t + 2, hb[0], hb[1], 2)
        K2_STEP(t + 3, hb[1], hb[0], 3)
        K2_STEP(t + 4, hb[0], hb[1], 4)
        K2_STEP(t + 5, hb[1], hb[0], 5)
        K2_STEP(t + 6, hb[0], hb[1], 6)
        K2_STEP(t + 7, hb[1], hb[0], 7)
    }
#undef K2_STEP
}

// ---------------------------------------------------------------------------
// K3: out[TB][128](f32) = hs[TB][256](f16) @ W_out^T + b_out   (MFMA C^T)
// 1024 WGs x 8 row-tiles; next-tile loads in flight across epilogue.
// ---------------------------------------------------------------------------
__global__ __launch_bounds__(256, 2) void k3_out(
    const _Float16* __restrict__ hs,
    const float* __restrict__ w_out,
    const float* __restrict__ b_out,
    float* __restrict__ out)
{
    const int tid = threadIdx.x;
    const int lane = tid & 63, wave = tid >> 6;
    const int m = lane & 15, quad = lane >> 4;

    h8 af[2][8];
    #pragma unroll
    for (int i = 0; i < 2; ++i)
        #pragma unroll
        for (int kt = 0; kt < 8; ++kt)
            af[i][kt] = ld_cvt8(w_out + (size_t)(wave*32 + i*16 + m) * H_ + kt*32 + quad*8);

    float bias[2][4];
    #pragma unroll
    for (int i = 0; i < 2; ++i)
        #pragma unroll
        for (int r = 0; r < 4; ++r)
            bias[i][r] = b_out[wave*32 + i*16 + quad*4 + r];

    __shared__ __align__(16) float st[2][16][132];

    h8 bf[8];
    {
        const size_t n0 = (size_t)blockIdx.x * 128;
        #pragma unroll
        for (int kt = 0; kt < 8; ++kt)
            bf[kt] = *(const h8*)(hs + (n0 + m) * H_ + kt*32 + quad*8);
    }

    for (int rt = 0; rt < 8; ++rt) {
        const size_t n0 = (size_t)blockIdx.x * 128 + rt * 16;

        h8 cur[8];
        #pragma unroll
        for (int kt = 0; kt < 8; ++kt) cur[kt] = bf[kt];

        if (rt < 7) {
            #pragma unroll
            for (int kt = 0; kt < 8; ++kt)
                bf[kt] = *(const h8*)(hs + (n0 + 16 + m) * H_ + kt*32 + quad*8);
        }

        f32x4 acc[2];
        #pragma unroll
        for (int i = 0; i < 2; ++i) acc[i] = (f32x4){0,0,0,0};
        #pragma unroll
        for (int i = 0; i < 2; ++i)
            #pragma unroll
            for (int kt = 0; kt < 8; ++kt)
                acc[i] = __builtin_amdgcn_mfma_f32_16x16x32_f16(af[i][kt], cur[kt], acc[i], 0, 0, 0);

        const int p = rt & 1;
        #pragma unroll
        for (int i = 0; i < 2; ++i) {
            f32x4 v;
            #pragma unroll
            for (int r = 0; r < 4; ++r) v[r] = acc[i][r] + bias[i][r];
            *(f32x4*)&st[p][m][wave*32 + i*16 + quad*4] = v;
        }
        BAR_LGKM();
        #pragma unroll
        for (int it = 0; it < 2; ++it) {
            int idx = tid + it*256;
            int r = idx >> 5, c4 = (idx & 31) * 4;
            f32x4 v = *(const f32x4*)&st[p][r][c4];
            *(f32x4*)(out + (n0 + r) * NOUT_ + c4) = v;
        }
    }
}

extern "C" void kernel_launch(void* const* d_in, const int* in_sizes, int n_in,
                              void* d_out, int out_size, void* d_ws, size_t ws_size,
                              hipStream_t stream) {
    const float* x     = (const float*)d_in[0];
    const float* w_ih  = (const float*)d_in[1];
    const float* w_hh  = (const float*)d_in[2];
    const float* b_ih  = (const float*)d_in[3];
    const float* b_hh  = (const float*)d_in[4];
    const float* w_out = (const float*)d_in[5];
    const float* b_out = (const float*)d_in[6];

    _Float16* xp    = (_Float16*)d_ws;                 // 67.1 MB
    _Float16* hsbuf = xp + (size_t)TB_ * H_;           // 67.1 MB

    k1_xproj<<<1024, 256, 0, stream>>>(x, w_ih, b_ih, b_hh, xp);
    k2_scan <<<B_,   256, 0, stream>>>(xp, w_hh, hsbuf);
    k3_out  <<<1024, 256, 0, stream>>>(hsbuf, w_out, b_out, (float*)d_out);
}

// Round 7
// 1045.474 us; speedup vs baseline: 1.1004x; 1.0702x over previous
//
#include <hip/hip_runtime.h>
#include <hip/hip_bf16.h>
#include <hip/hip_fp16.h>

#define T_ 2048
#define B_ 64
#define NIN_ 128
#define H_ 256
#define NOUT_ 128
#define TB_ (T_*B_)
#define BH_ (B_*H_)
#define TBLK_ (T_/8)   // 256 blocks of 8 timesteps

typedef _Float16 h8 __attribute__((ext_vector_type(8)));
typedef _Float16 h4 __attribute__((ext_vector_type(4)));
typedef float f32x4 __attribute__((ext_vector_type(4)));

// LDS-only barrier: do NOT drain vmcnt (global loads/stores stay in flight).
#define BAR_LGKM() asm volatile("s_waitcnt lgkmcnt(0)\n\ts_barrier" ::: "memory")

__device__ __forceinline__ h8 cvt8(float4 a, float4 b) {
    h8 r;
    r[0] = (_Float16)a.x; r[1] = (_Float16)a.y; r[2] = (_Float16)a.z; r[3] = (_Float16)a.w;
    r[4] = (_Float16)b.x; r[5] = (_Float16)b.y; r[6] = (_Float16)b.z; r[7] = (_Float16)b.w;
    return r;
}
__device__ __forceinline__ h8 ld_cvt8(const float* __restrict__ p) {
    const float4* q = (const float4*)p;
    return cvt8(q[0], q[1]);
}

// ---------------------------------------------------------------------------
// K1: xp2[b][t/8][j][t%8] (f16) = x[t][b][:] @ W_ih^T + (b_ih+b_hh)
// Tile = 16 t-values at fixed b. Transposing epilogue via LDS st2[j][t]
// (stride 24 f16 -> <=2-way bank aliasing), coalesced uint4 global writes.
// Grid 1024 = 64 b x 16 t-chunks; 8 tiles per WG.
// ---------------------------------------------------------------------------
__global__ __launch_bounds__(256, 2) void k1_xproj(
    const float* __restrict__ x,
    const float* __restrict__ w_ih,
    const float* __restrict__ b_ih,
    const float* __restrict__ b_hh,
    _Float16* __restrict__ xp2)
{
    const int tid = threadIdx.x;
    const int lane = tid & 63, wave = tid >> 6;
    const int m = lane & 15, quad = lane >> 4;
    const int b  = blockIdx.x >> 4;
    const int tc = blockIdx.x & 15;

    h8 af[4][4];
    #pragma unroll
    for (int i = 0; i < 4; ++i)
        #pragma unroll
        for (int kt = 0; kt < 4; ++kt)
            af[i][kt] = ld_cvt8(w_ih + (size_t)(wave*64 + i*16 + m) * NIN_ + kt*32 + quad*8);

    float bias[4][4];
    #pragma unroll
    for (int i = 0; i < 4; ++i)
        #pragma unroll
        for (int r = 0; r < 4; ++r) {
            int c = wave*64 + i*16 + quad*4 + r;
            bias[i][r] = b_ih[c] + b_hh[c];
        }

    __shared__ __align__(16) _Float16 st2[2][256 * 24];   // [j][t] stride 24

    float4 xr[4][2];
    {
        const int t0 = tc * 128;
        #pragma unroll
        for (int kt = 0; kt < 4; ++kt) {
            const float4* q = (const float4*)(x + ((size_t)(t0 + m) * B_ + b) * NIN_ + kt*32 + quad*8);
            xr[kt][0] = q[0]; xr[kt][1] = q[1];
        }
    }

    for (int rt = 0; rt < 8; ++rt) {
        const int t0 = tc * 128 + rt * 16;

        h8 bf[4];
        #pragma unroll
        for (int kt = 0; kt < 4; ++kt) bf[kt] = cvt8(xr[kt][0], xr[kt][1]);

        if (rt < 7) {
            #pragma unroll
            for (int kt = 0; kt < 4; ++kt) {
                const float4* q = (const float4*)(x + ((size_t)(t0 + 16 + m) * B_ + b) * NIN_ + kt*32 + quad*8);
                xr[kt][0] = q[0]; xr[kt][1] = q[1];
            }
        }

        f32x4 acc[4];
        #pragma unroll
        for (int i = 0; i < 4; ++i) acc[i] = (f32x4){0,0,0,0};
        #pragma unroll
        for (int i = 0; i < 4; ++i)
            #pragma unroll
            for (int kt = 0; kt < 4; ++kt)
                acc[i] = __builtin_amdgcn_mfma_f32_16x16x32_f16(af[i][kt], bf[kt], acc[i], 0, 0, 0);

        const int p = rt & 1;
        // value (j = wave*64+i*16+quad*4+r, t-col = m) -> st2[j*24 + m]
        #pragma unroll
        for (int i = 0; i < 4; ++i)
            #pragma unroll
            for (int r = 0; r < 4; ++r) {
                int j = wave*64 + i*16 + quad*4 + r;
                st2[p][j*24 + m] = (_Float16)(acc[i][r] + bias[i][r]);
            }
        BAR_LGKM();
        // thread tid = j: 32 B LDS -> two coalesced uint4 global writes
        {
            const int j = tid;
            const h8* row = (const h8*)&st2[p][j*24];
            h8 v0 = row[0], v1 = row[1];
            const int blk = t0 >> 3;
            _Float16* dst = xp2 + ((size_t)(b * TBLK_ + blk) * H_ + j) * 8;
            *(h8*)dst            = v0;
            *(h8*)(dst + H_*8)   = v1;
        }
    }
}

// ---------------------------------------------------------------------------
// K2: sequential scan via MFMA, 64 WGs (one batch each), 256 threads.
// A = h broadcast to all 16 M-rows (quad-uniform b128 LDS reads);
// B = W_hh static B-frags (128 VGPRs); no cross-lane reduce.
// xp2 is consumed one uint4 (8 timesteps) per lane per 8-step block,
// loaded one full block ahead -> no same-step global wait.
// h double-buffered in LDS; 1 lgkm-only barrier/step.
// ---------------------------------------------------------------------------
__global__ __launch_bounds__(256, 1) void k2_scan(
    const _Float16* __restrict__ xp2,      // [B][T/8][H][8] f16
    const float* __restrict__ w_hh,        // [H][H] f32
    _Float16* __restrict__ hs)             // [T][B][H] f16
{
    const int tid = threadIdx.x;
    const int lane = tid & 63, wave = tid >> 6;
    const int n = lane & 15, quad = lane >> 4;
    const int b = blockIdx.x;
    const int j = wave*64 + quad*16 + n;    // owned output column

    // B-frags (W_hh), 128 VGPRs
    h8 bf[4][8];
    #pragma unroll
    for (int q = 0; q < 4; ++q)
        #pragma unroll
        for (int kt = 0; kt < 8; ++kt)
            bf[q][kt] = ld_cvt8(w_hh + (size_t)(wave*64 + q*16 + n) * H_ + kt*32 + quad*8);

    __shared__ __align__(16) _Float16 hb[2][256];
    hb[0][tid] = (_Float16)0.0f;
    __syncthreads();

    const _Float16* xq = xp2 + ((size_t)b * TBLK_ * H_ + j) * 8;
    _Float16*       hsl = hs + (size_t)b * H_ + j;

    h8 pf = *(const h8*)xq;                 // block 0

#define K2_STEP(T, RB, WB, XV)                                                 \
    {                                                                          \
        const h8* hp = (const h8*)&RB[0];                                      \
        h8 av[8];                                                              \
        _Pragma("unroll")                                                      \
        for (int kt = 0; kt < 8; ++kt) av[kt] = hp[kt*4 + quad];               \
        f32x4 acc[4];                                                          \
        _Pragma("unroll")                                                      \
        for (int q = 0; q < 4; ++q) acc[q] = (f32x4){0,0,0,0};                 \
        _Pragma("unroll")                                                      \
        for (int kt = 0; kt < 8; ++kt)                                         \
            _Pragma("unroll")                                                  \
            for (int q = 0; q < 4; ++q)                                        \
                acc[q] = __builtin_amdgcn_mfma_f32_16x16x32_f16(av[kt], bf[q][kt], acc[q], 0, 0, 0); \
        float v0 = acc[0][0], v1 = acc[1][0], v2 = acc[2][0], v3 = acc[3][0];  \
        float va = (quad & 1) ? v1 : v0;                                       \
        float vb = (quad & 1) ? v3 : v2;                                       \
        float vv = (quad & 2) ? vb : va;                                       \
        float sv = vv + (XV);                                                  \
        float e  = __expf(2.0f * sv);                                          \
        float hn = fmaf(-2.0f, __builtin_amdgcn_rcpf(e + 1.0f), 1.0f);         \
        _Float16 h16 = (_Float16)hn;                                           \
        WB[j] = h16;                                                           \
        hsl[(size_t)(T) * BH_] = h16;                                          \
        BAR_LGKM();                                                            \
    }

    for (int tb = 0; tb < TBLK_; ++tb) {
        h8 cur = pf;                         // waits on load issued 1 block ago
        const int tnb = (tb + 1 < TBLK_) ? tb + 1 : TBLK_ - 1;
        pf = *(const h8*)(xq + (size_t)tnb * (H_ * 8));   // in flight for 8 steps
        const int t = tb * 8;
        K2_STEP(t + 0, hb[0], hb[1], (float)cur[0])
        K2_STEP(t + 1, hb[1], hb[0], (float)cur[1])
        K2_STEP(t + 2, hb[0], hb[1], (float)cur[2])
        K2_STEP(t + 3, hb[1], hb[0], (float)cur[3])
        K2_STEP(t + 4, hb[0], hb[1], (float)cur[4])
        K2_STEP(t + 5, hb[1], hb[0], (float)cur[5])
        K2_STEP(t + 6, hb[0], hb[1], (float)cur[6])
        K2_STEP(t + 7, hb[1], hb[0], (float)cur[7])
    }
#undef K2_STEP
}

// ---------------------------------------------------------------------------
// K3: out[TB][128](f32) = hs[TB][256](f16) @ W_out^T + b_out   (MFMA C^T)
// 1024 WGs x 8 row-tiles; next-tile loads in flight across epilogue.
// ---------------------------------------------------------------------------
__global__ __launch_bounds__(256, 2) void k3_out(
    const _Float16* __restrict__ hs,
    const float* __restrict__ w_out,
    const float* __restrict__ b_out,
    float* __restrict__ out)
{
    const int tid = threadIdx.x;
    const int lane = tid & 63, wave = tid >> 6;
    const int m = lane & 15, quad = lane >> 4;

    h8 af[2][8];
    #pragma unroll
    for (int i = 0; i < 2; ++i)
        #pragma unroll
        for (int kt = 0; kt < 8; ++kt)
            af[i][kt] = ld_cvt8(w_out + (size_t)(wave*32 + i*16 + m) * H_ + kt*32 + quad*8);

    float bias[2][4];
    #pragma unroll
    for (int i = 0; i < 2; ++i)
        #pragma unroll
        for (int r = 0; r < 4; ++r)
            bias[i][r] = b_out[wave*32 + i*16 + quad*4 + r];

    __shared__ __align__(16) float st[2][16][132];

    h8 bf[8];
    {
        const size_t n0 = (size_t)blockIdx.x * 128;
        #pragma unroll
        for (int kt = 0; kt < 8; ++kt)
            bf[kt] = *(const h8*)(hs + (n0 + m) * H_ + kt*32 + quad*8);
    }

    for (int rt = 0; rt < 8; ++rt) {
        const size_t n0 = (size_t)blockIdx.x * 128 + rt * 16;

        h8 cur[8];
        #pragma unroll
        for (int kt = 0; kt < 8; ++kt) cur[kt] = bf[kt];

        if (rt < 7) {
            #pragma unroll
            for (int kt = 0; kt < 8; ++kt)
                bf[kt] = *(const h8*)(hs + (n0 + 16 + m) * H_ + kt*32 + quad*8);
        }

        f32x4 acc[2];
        #pragma unroll
        for (int i = 0; i < 2; ++i) acc[i] = (f32x4){0,0,0,0};
        #pragma unroll
        for (int i = 0; i < 2; ++i)
            #pragma unroll
            for (int kt = 0; kt < 8; ++kt)
                acc[i] = __builtin_amdgcn_mfma_f32_16x16x32_f16(af[i][kt], cur[kt], acc[i], 0, 0, 0);

        const int p = rt & 1;
        #pragma unroll
        for (int i = 0; i < 2; ++i) {
            f32x4 v;
            #pragma unroll
            for (int r = 0; r < 4; ++r) v[r] = acc[i][r] + bias[i][r];
            *(f32x4*)&st[p][m][wave*32 + i*16 + quad*4] = v;
        }
        BAR_LGKM();
        #pragma unroll
        for (int it = 0; it < 2; ++it) {
            int idx = tid + it*256;
            int r = idx >> 5, c4 = (idx & 31) * 4;
            f32x4 v = *(const f32x4*)&st[p][r][c4];
            *(f32x4*)(out + (n0 + r) * NOUT_ + c4) = v;
        }
    }
}

extern "C" void kernel_launch(void* const* d_in, const int* in_sizes, int n_in,
                              void* d_out, int out_size, void* d_ws, size_t ws_size,
                              hipStream_t stream) {
    const float* x     = (const float*)d_in[0];
    const float* w_ih  = (const float*)d_in[1];
    const float* w_hh  = (const float*)d_in[2];
    const float* b_ih  = (const float*)d_in[3];
    const float* b_hh  = (const float*)d_in[4];
    const float* w_out = (const float*)d_in[5];
    const float* b_out = (const float*)d_in[6];

    _Float16* xp2   = (_Float16*)d_ws;                 // 67.1 MB [B][T/8][H][8]
    _Float16* hsbuf = xp2 + (size_t)TB_ * H_;          // 67.1 MB [T][B][H]

    k1_xproj<<<1024, 256, 0, stream>>>(x, w_ih, b_ih, b_hh, xp2);
    k2_scan <<<B_,   256, 0, stream>>>(xp2, w_hh, hsbuf);
    k3_out  <<<1024, 256, 0, stream>>>(hsbuf, w_out, b_out, (float*)d_out);
}